// Round 4
// baseline (154.271 us; speedup 1.0000x reference)
//
#include <hip/hip_runtime.h>

namespace {
constexpr int DEPTH    = 11;
constexpr int IN_W     = 768;
constexpr int LEAF_W   = 16;
constexpr int OUT_W    = 768;
constexpr int N_NODES  = (1 << DEPTH) - 1;   // 2047
constexpr int N_LEAVES = (1 << DEPTH);       // 2048
constexpr int BATCH    = 8192;
constexpr int G        = 4;                  // samples per wave in the MLP
constexpr int MAX_TASKS = (BATCH + (G - 1) * N_LEAVES) / G;  // 3584
}

// ---------------- Kernel A: tree routing (one wave per sample) ----------------
// fp64 accumulation keeps decision-boundary error (~3e-8) far below the fp32
// numpy reference's own rounding (~1e-7) -> routing decisions match.
__global__ __launch_bounds__(256) void fff_route(
    const float* __restrict__ x,
    const float* __restrict__ nw,
    const float* __restrict__ nb,
    int* __restrict__ leaf_of,   // [BATCH]
    int* __restrict__ rank_of,   // [BATCH]
    int* __restrict__ cnt)       // [N_LEAVES], pre-zeroed
{
    const int lane = threadIdx.x & 63;
    const int s    = (int)((blockIdx.x * blockDim.x + threadIdx.x) >> 6);

    const float* xp = x + (size_t)s * IN_W + lane * 12;
    const float4 xv0 = *(const float4*)(xp + 0);
    const float4 xv1 = *(const float4*)(xp + 4);
    const float4 xv2 = *(const float4*)(xp + 8);
    const float xs[12] = {xv0.x, xv0.y, xv0.z, xv0.w,
                          xv1.x, xv1.y, xv1.z, xv1.w,
                          xv2.x, xv2.y, xv2.z, xv2.w};

    int node = 0;
    #pragma unroll 1
    for (int d = 0; d < DEPTH; ++d) {
        const float* wp = nw + (size_t)node * IN_W + lane * 12;
        const float4 a0 = *(const float4*)(wp + 0);
        const float4 a1 = *(const float4*)(wp + 4);
        const float4 a2 = *(const float4*)(wp + 8);
        const float wa[12] = {a0.x, a0.y, a0.z, a0.w,
                              a1.x, a1.y, a1.z, a1.w,
                              a2.x, a2.y, a2.z, a2.w};
        double acc = 0.0;
        #pragma unroll
        for (int j = 0; j < 12; ++j)
            acc = fma((double)wa[j], (double)xs[j], acc);
        #pragma unroll
        for (int off = 32; off > 0; off >>= 1)
            acc += __shfl_xor(acc, off, 64);
        const double score = acc + (double)nb[node];
        node = 2 * node + 1 + (score >= 0.0 ? 1 : 0);
    }
    const int leaf = node - N_NODES;

    if (lane == 0) {
        leaf_of[s] = leaf;
        rank_of[s] = atomicAdd(&cnt[leaf], 1);
    }
}

// ------- Kernel B: dual exclusive scan (sample offsets + group offsets) -------
__global__ void fff_scan(const int* __restrict__ cnt,
                         int* __restrict__ off,
                         int* __restrict__ goff,
                         int* __restrict__ ntasks)
{
    const int lane = threadIdx.x & 63;        // launched with 64 threads
    const int base = lane * (N_LEAVES / 64);  // 32 leaves per lane
    int c[N_LEAVES / 64], gl[N_LEAVES / 64];
    int s1 = 0, s2 = 0;
    #pragma unroll
    for (int i = 0; i < N_LEAVES / 64; ++i) {
        c[i] = cnt[base + i]; s1 += c[i];
        gl[i] = (c[i] + G - 1) / G; s2 += gl[i];
    }
    int v1 = s1, v2 = s2;
    #pragma unroll
    for (int d = 1; d < 64; d <<= 1) {
        int u1 = __shfl_up(v1, d, 64);
        int u2 = __shfl_up(v2, d, 64);
        if (lane >= d) { v1 += u1; v2 += u2; }
    }
    int r1 = v1 - s1, r2 = v2 - s2;   // exclusive prefixes
    #pragma unroll
    for (int i = 0; i < N_LEAVES / 64; ++i) {
        off[base + i]  = r1; r1 += c[i];
        goff[base + i] = r2; r2 += gl[i];
    }
    if (lane == 63) *ntasks = v2;
}

// ---------------- Kernel C: scatter samples into leaf-sorted order ----------------
__global__ __launch_bounds__(256) void fff_scatter(
    const int* __restrict__ leaf_of, const int* __restrict__ rank_of,
    const int* __restrict__ off,
    int* __restrict__ sorted, int* __restrict__ leaf_sorted)
{
    const int s = blockIdx.x * blockDim.x + threadIdx.x;
    if (s < BATCH) {
        const int lf = leaf_of[s];
        const int i  = off[lf] + rank_of[s];
        sorted[i]      = s;
        leaf_sorted[i] = lf;
    }
}

// ---------------- Kernel C2: emit per-group tasks (one thread per leaf) ----------------
__global__ __launch_bounds__(256) void fff_tasks(
    const int* __restrict__ cnt, const int* __restrict__ off,
    const int* __restrict__ goff, int2* __restrict__ tasks)
{
    const int l = blockIdx.x * blockDim.x + threadIdx.x;
    if (l < N_LEAVES) {
        int n = cnt[l], o = off[l];
        int g0 = goff[l];
        for (int j = 0; n > 0; ++j, n -= G, o += G)
            tasks[g0 + j] = make_int2(o, n < G ? n : G);
    }
}

// -------- Kernel D: leaf MLP, one wave per group of up to 4 same-leaf samples --------
// Weight fragments are loaded once per group and applied to 4 samples ->
// per-sample VMEM requests drop ~70 -> ~27 and weight request bytes drop 4x.
__global__ __launch_bounds__(256, 2) void fff_mlp4(
    const float* __restrict__ x,
    const float* __restrict__ w1,
    const float* __restrict__ b1,
    const float* __restrict__ w2,
    const int* __restrict__ sorted,
    const int* __restrict__ leaf_sorted,
    const int2* __restrict__ tasks,
    const int* __restrict__ ntasks_p,
    float* __restrict__ out)
{
    const int lane = threadIdx.x & 63;
    const int t    = (int)((blockIdx.x * blockDim.x + threadIdx.x) >> 6);
    const int nt   = *ntasks_p;
    if (t >= nt) return;

    const int2 task = tasks[t];
    const int start = task.x;
    const int n     = task.y;            // 1..4, wave-uniform
    const int leaf  = leaf_sorted[start];

    int sidx[G];
    #pragma unroll
    for (int g = 0; g < G; ++g)
        sidx[g] = sorted[start + (g < n ? g : n - 1)];   // replicate last for padding

    float xs[G][12];
    #pragma unroll
    for (int g = 0; g < G; ++g) {
        const float* xp = x + (size_t)sidx[g] * IN_W + lane * 12;
        const float4 v0 = *(const float4*)(xp + 0);
        const float4 v1 = *(const float4*)(xp + 4);
        const float4 v2 = *(const float4*)(xp + 8);
        xs[g][0]=v0.x; xs[g][1]=v0.y; xs[g][2]=v0.z;  xs[g][3]=v0.w;
        xs[g][4]=v1.x; xs[g][5]=v1.y; xs[g][6]=v1.z;  xs[g][7]=v1.w;
        xs[g][8]=v2.x; xs[g][9]=v2.y; xs[g][10]=v2.z; xs[g][11]=v2.w;
    }

    // ---- layer 1: lane owns 12 w1 rows; apply each row to all 4 samples ----
    const float* w1p = w1 + (size_t)leaf * (IN_W * LEAF_W) + (size_t)lane * 12 * LEAF_W;
    float h[G][LEAF_W];
    #pragma unroll
    for (int g = 0; g < G; ++g)
        #pragma unroll
        for (int l = 0; l < LEAF_W; ++l) h[g][l] = 0.f;

    #pragma unroll
    for (int r = 0; r < 12; ++r) {
        const float4 c0 = *(const float4*)(w1p + r * LEAF_W + 0);
        const float4 c1 = *(const float4*)(w1p + r * LEAF_W + 4);
        const float4 c2 = *(const float4*)(w1p + r * LEAF_W + 8);
        const float4 c3 = *(const float4*)(w1p + r * LEAF_W + 12);
        const float c[16] = {c0.x, c0.y, c0.z, c0.w, c1.x, c1.y, c1.z, c1.w,
                             c2.x, c2.y, c2.z, c2.w, c3.x, c3.y, c3.z, c3.w};
        #pragma unroll
        for (int g = 0; g < G; ++g) {
            const float xi = xs[g][r];
            #pragma unroll
            for (int l = 0; l < LEAF_W; ++l) h[g][l] = fmaf(xi, c[l], h[g][l]);
        }
    }

    // reduce across 64 lanes (butterfly; identical result on all lanes)
    #pragma unroll
    for (int g = 0; g < G; ++g) {
        #pragma unroll
        for (int l = 0; l < LEAF_W; ++l) {
            float v = h[g][l];
            #pragma unroll
            for (int o2 = 32; o2 > 0; o2 >>= 1) v += __shfl_xor(v, o2, 64);
            h[g][l] = v;
        }
    }
    const float* b1p = b1 + (size_t)leaf * LEAF_W;
    #pragma unroll
    for (int l = 0; l < LEAF_W; ++l) {
        const float bl = b1p[l];
        #pragma unroll
        for (int g = 0; g < G; ++g) h[g][l] = fmaxf(h[g][l] + bl, 0.f);
    }

    // ---- layer 2: lane owns 12 output cols; each w2 row applied to 4 samples ----
    const float* w2p = w2 + (size_t)leaf * (LEAF_W * OUT_W) + lane * 12;
    float oacc[G][12];
    #pragma unroll
    for (int g = 0; g < G; ++g)
        #pragma unroll
        for (int j = 0; j < 12; ++j) oacc[g][j] = 0.f;

    #pragma unroll
    for (int l = 0; l < LEAF_W; ++l) {
        const float4 r0 = *(const float4*)(w2p + l * OUT_W + 0);
        const float4 r1 = *(const float4*)(w2p + l * OUT_W + 4);
        const float4 r2 = *(const float4*)(w2p + l * OUT_W + 8);
        const float rr[12] = {r0.x, r0.y, r0.z, r0.w,
                              r1.x, r1.y, r1.z, r1.w,
                              r2.x, r2.y, r2.z, r2.w};
        #pragma unroll
        for (int g = 0; g < G; ++g) {
            const float hl = h[g][l];
            #pragma unroll
            for (int j = 0; j < 12; ++j) oacc[g][j] = fmaf(hl, rr[j], oacc[g][j]);
        }
    }

    #pragma unroll
    for (int g = 0; g < G; ++g) {
        if (g < n) {
            float* op = out + (size_t)sidx[g] * OUT_W + lane * 12;
            *(float4*)(op + 0) = make_float4(oacc[g][0], oacc[g][1], oacc[g][2],  oacc[g][3]);
            *(float4*)(op + 4) = make_float4(oacc[g][4], oacc[g][5], oacc[g][6],  oacc[g][7]);
            *(float4*)(op + 8) = make_float4(oacc[g][8], oacc[g][9], oacc[g][10], oacc[g][11]);
        }
    }
}

extern "C" void kernel_launch(void* const* d_in, const int* in_sizes, int n_in,
                              void* d_out, int out_size, void* d_ws, size_t ws_size,
                              hipStream_t stream) {
    const float* x  = (const float*)d_in[0];
    const float* nw = (const float*)d_in[1];
    const float* nb = (const float*)d_in[2];
    const float* w1 = (const float*)d_in[3];
    const float* b1 = (const float*)d_in[4];
    const float* w2 = (const float*)d_in[5];
    float* o        = (float*)d_out;

    // ws (ints): cnt[2048] off[2048] goff[2048] ntasks[1]+pad[7] leaf[8192] rank[8192]
    //            sorted[8192] leafs[8192] tasks[2*3584]
    int* cnt    = (int*)d_ws;
    int* off    = cnt + N_LEAVES;
    int* goff   = off + N_LEAVES;
    int* ntasks = goff + N_LEAVES;
    int* leaf   = ntasks + 8;
    int* rank   = leaf + BATCH;
    int* sorted = rank + BATCH;
    int* leafs  = sorted + BATCH;
    int2* tasks = (int2*)(leafs + BATCH);

    hipMemsetAsync(cnt, 0, N_LEAVES * sizeof(int), stream);

    fff_route  <<<dim3(BATCH / 4),  dim3(256), 0, stream>>>(x, nw, nb, leaf, rank, cnt);
    fff_scan   <<<dim3(1),          dim3(64),  0, stream>>>(cnt, off, goff, ntasks);
    fff_scatter<<<dim3(BATCH/256),  dim3(256), 0, stream>>>(leaf, rank, off, sorted, leafs);
    fff_tasks  <<<dim3(N_LEAVES/256), dim3(256), 0, stream>>>(cnt, off, goff, tasks);
    fff_mlp4   <<<dim3((MAX_TASKS * 64 + 255) / 256), dim3(256), 0, stream>>>(
        x, w1, b1, w2, sorted, leafs, tasks, ntasks, o);
}